// Round 11
// baseline (377.907 us; speedup 1.0000x reference)
//
#include <hip/hip_runtime.h>

#define ALPHA_MIN 0.8187307530779818f  // exp(-1/5)
#define ALPHA_MAX 0.9607894391523232f  // exp(-1/25)

typedef _Float16 f16;
typedef _Float16 f16x4 __attribute__((ext_vector_type(4)));
typedef _Float16 f16x8 __attribute__((ext_vector_type(8)));
typedef float f32x16 __attribute__((ext_vector_type(16)));

// Fixed problem shape
#define BB_ 32
#define TT_ 2048
#define KK_ 256
#define HH_ 512

// ====================== kernel 0: W hi/lo split (tiny) ======================
// W (512x256 f32) -> Whi/Wlo f16 planes (512 KB total) so GEMM blocks load
// W-fragments directly with ZERO cvt VALU and no per-block W conversion
// redundancy. Same split formula as the verified kernel -> identical bits.
__global__ __launch_bounds__(256) void w_split(
    const float* __restrict__ W, f16* __restrict__ Whi, f16* __restrict__ Wlo)
{
    const int i = (blockIdx.x * 256 + threadIdx.x) * 4;   // grid 128: 131072 elems
    const float4 v = *(const float4*)(W + i);
    const float vv[4] = {v.x, v.y, v.z, v.w};
    f16x4 h, l;
#pragma unroll
    for (int e = 0; e < 4; ++e) {
        const f16 he = (f16)vv[e];
        h[e] = he;
        l[e] = (f16)((vv[e] - (float)he) * 2048.0f);
    }
    *(f16x4*)(Whi + i) = h;
    *(f16x4*)(Wlo + i) = l;
}

// ====================== kernel 1: single-chunk tile GEMM ====================
// R10/R11 (resubmitted after infra failure; kernel audited, unchanged):
// 10 rounds established that phase cost is ~4-5k cyc REGARDLESS of content
// (content ~500 cyc), in every persistent phase-coupled block structure, at
// every blocks/CU. The near-roofline kernels (scan, 4.9 TB/s) are the
// opposite shape: tiny independent work units, deep MLP, no coupling.
// This GEMM adopts that shape: each block = ONE 32t x 256h tile = one staging
// phase + ONE barrier + 48 MFMA/wave, then retires. 4096 blocks; phase
// overhead paid once per block, overlapped across blocks by the dispatcher.
//   block 512 = 8 waves; wave wv owns h-cols h0 = hh*256 + wv*32 .. +31.
//   W-frags: direct f16x8 loads from Whi/Wlo planes (no cvt).
//   X chunk (32t x 256k): 4 coalesced dwordx4 loads/thread -> hi/lo split ->
//   XOR-swizzled LDS ((row&7)<<3 f16-units, both sides) -> ds_read_b128.
// fp16-split: C = Ah*Bh + 2^-11*(Ah*Bl + Al*Bh); bit-identical fragments,
// MFMA order (ks=0..15), and epilogue row mapping vs the verified kernel.
__global__ __launch_bounds__(512, 1) void wx_gemm_tile(
    const float* __restrict__ X,      // (B,T,K)
    const f16* __restrict__ Whi,      // (H,K) f16 hi plane
    const f16* __restrict__ Wlo,      // (H,K) f16 lo plane
    float* __restrict__ out)          // (B,T,H) <- Wx
{
    __shared__ f16 Ah[32 * 256];      // 16 KB
    __shared__ f16 Al[32 * 256];      // 16 KB

    const int bid = blockIdx.x;
    const int b   = bid & 31;         // XCD = b%8: the 128 chunk-blocks of
    const int ck  = bid >> 5;         // batch b share X[b] in one XCD L2
    const int hh  = ck & 1;           // h-half (0: h<256, 1: h>=256)
    const int tc  = ck >> 1;          // 0..63 t-chunk
    const int t0  = tc * 32;

    const int tid  = threadIdx.x;
    const int wv   = tid >> 6;        // 0..7
    const int lane = tid & 63;
    const int fm   = lane & 31;
    const int fq   = lane >> 5;

    const int h0 = hh * 256 + wv * 32;

    // ---- W fragments: direct f16 vector loads, no conversion --------------
    f16x8 bh[16], bl[16];
    {
        const f16* wph = Whi + (size_t)(h0 + fm) * KK_ + fq * 8;
        const f16* wpl = Wlo + (size_t)(h0 + fm) * KK_ + fq * 8;
#pragma unroll
        for (int ks = 0; ks < 16; ++ks) {
            bh[ks] = *(const f16x8*)(wph + ks * 16);
            bl[ks] = *(const f16x8*)(wpl + ks * 16);
        }
    }

    // ---- stage X chunk: 2048 slots of 4 floats, fully coalesced -----------
    {
        const float* xb = X + ((size_t)b * TT_ + t0) * KK_;
        float4 v[4];
#pragma unroll
        for (int i = 0; i < 4; ++i)
            v[i] = *(const float4*)(xb + (size_t)(tid + i * 512) * 4);
#pragma unroll
        for (int i = 0; i < 4; ++i) {
            const int s  = tid + i * 512;          // slot 0..2047
            const int r  = s >> 6;                 // t-row 0..31
            const int k0 = (s & 63) * 4;           // f16-unit col
            const int kk = k0 ^ ((r & 7) << 3);    // XOR swizzle (bank spread)
            const float vv[4] = {v[i].x, v[i].y, v[i].z, v[i].w};
            f16x4 h, l;
#pragma unroll
            for (int e = 0; e < 4; ++e) {
                const f16 he = (f16)vv[e];
                h[e] = he;
                l[e] = (f16)((vv[e] - (float)he) * 2048.0f);
            }
            *(f16x4*)&Ah[r * 256 + kk] = h;
            *(f16x4*)&Al[r * 256 + kk] = l;
        }
    }
    __syncthreads();                  // the block's ONE barrier

    // ---- 48 MFMA: 16 k-steps x 3 accumulators -----------------------------
    f32x16 accH, accLa, accLb;
#pragma unroll
    for (int e = 0; e < 16; ++e) { accH[e] = 0.0f; accLa[e] = 0.0f; accLb[e] = 0.0f; }

    const int rsw = (fm & 7) << 3;
#pragma unroll
    for (int ks = 0; ks < 16; ++ks) {
        const int kk = (ks * 16 + fq * 8) ^ rsw;
        const f16x8 ah = *(const f16x8*)&Ah[fm * 256 + kk];
        const f16x8 al = *(const f16x8*)&Al[fm * 256 + kk];
        accH  = __builtin_amdgcn_mfma_f32_32x32x16_f16(ah, bh[ks], accH,  0, 0, 0);
        accLa = __builtin_amdgcn_mfma_f32_32x32x16_f16(ah, bl[ks], accLa, 0, 0, 0);
        accLb = __builtin_amdgcn_mfma_f32_32x32x16_f16(al, bh[ks], accLb, 0, 0, 0);
    }

    // ---- epilogue: proven row mapping, direct global stores ---------------
    float* op = out + ((size_t)b * TT_ + t0) * HH_ + h0 + fm;
#pragma unroll
    for (int r = 0; r < 16; ++r) {
        const int roww = (r & 3) + 8 * (r >> 2) + 4 * fq;
        op[(size_t)roww * HH_] = accH[r] + (accLa[r] + accLb[r]) * (1.0f / 2048.0f);
    }
}

// ============================ kernel 2: scan ================================
// R4's proven scan (~55 us, ~4.9 TB/s effective): 256 blocks x 64 threads,
// in-place on out, depth-32 A/B register prefetch. Unchanged.
__global__ __launch_bounds__(64) void lif_scan_opt(
    float* __restrict__ buf,          // (B,T,H): in Wx, out spikes
    const float* __restrict__ alpha,
    const float* __restrict__ u0,
    const float* __restrict__ s0)
{
    const int chain = blockIdx.x * 64 + threadIdx.x;   // 0..16383
    const int h = chain & (HH_ - 1);
    const int b = chain >> 9;
    float a = alpha[h];
    a = fminf(fmaxf(a, ALPHA_MIN), ALPHA_MAX);
    const float bbv = 1.0f - a;
    float u = u0[chain];
    float s = s0[chain];
    float* base = buf + (size_t)b * TT_ * HH_ + h;

    float wA[32], wB[32];
    auto loadA = [&](int t0) {
#pragma unroll
        for (int i = 0; i < 32; ++i) wA[i] = base[(size_t)(t0 + i) * HH_];
    };
    auto loadB = [&](int t0) {
#pragma unroll
        for (int i = 0; i < 32; ++i) wB[i] = base[(size_t)(t0 + i) * HH_];
    };
    auto stepA = [&](int t0) {
#pragma unroll
        for (int i = 0; i < 32; ++i) {
            u = fmaf(a, u - s, bbv * wA[i]);
            s = (u > 1.0f) ? 1.0f : 0.0f;
            base[(size_t)(t0 + i) * HH_] = s;
        }
    };
    auto stepB = [&](int t0) {
#pragma unroll
        for (int i = 0; i < 32; ++i) {
            u = fmaf(a, u - s, bbv * wB[i]);
            s = (u > 1.0f) ? 1.0f : 0.0f;
            base[(size_t)(t0 + i) * HH_] = s;
        }
    };

    loadA(0);
    for (int t0 = 0; t0 < TT_; t0 += 64) {
        loadB(t0 + 32);
        stepA(t0);
        if (t0 + 64 < TT_) loadA(t0 + 64);
        stepB(t0 + 32);
    }
}

// =================== generic fallback (non-reference shapes) ================
__global__ void gemm_naive(const float* __restrict__ X, const float* __restrict__ W,
                           float* __restrict__ C, int M, int N, int K)
{
    const int idx = blockIdx.x * 256 + threadIdx.x;
    if (idx >= M * N) return;
    const int m = idx / N, n = idx % N;
    float acc = 0.0f;
    for (int k = 0; k < K; ++k) acc = fmaf(X[(size_t)m * K + k], W[(size_t)n * K + k], acc);
    C[idx] = acc;
}

__global__ __launch_bounds__(64) void lif_scan_inplace(
    float* __restrict__ buf, const float* __restrict__ alpha,
    const float* __restrict__ u0, const float* __restrict__ s0, int T, int H)
{
    const int chain = blockIdx.x * 64 + threadIdx.x;
    const int h = chain % H;
    const int b = chain / H;
    float a = alpha[h];
    a = fminf(fmaxf(a, ALPHA_MIN), ALPHA_MAX);
    const float bb = 1.0f - a;
    float u = u0[chain], s = s0[chain];
    float* base = buf + (size_t)b * T * H + h;
    for (int t = 0; t < T; ++t) {
        u = fmaf(a, u - s, bb * base[(size_t)t * H]);
        s = (u > 1.0f) ? 1.0f : 0.0f;
        base[(size_t)t * H] = s;
    }
}

// ---------------- launch ----------------------------------------------------
extern "C" void kernel_launch(void* const* d_in, const int* in_sizes, int n_in,
                              void* d_out, int out_size, void* d_ws, size_t ws_size,
                              hipStream_t stream) {
    const float* x     = (const float*)d_in[0];
    const float* W     = (const float*)d_in[1];
    const float* alpha = (const float*)d_in[2];
    const float* u0    = (const float*)d_in[3];
    const float* s0    = (const float*)d_in[4];
    float* out = (float*)d_out;

    const int H = in_sizes[2];
    const int I = in_sizes[1] / H;
    const int B = in_sizes[3] / H;
    const int T = in_sizes[0] / (B * I);

    if (B == BB_ && T == TT_ && I == KK_ && H == HH_ && ws_size >= (1u << 20)) {
        f16* whi = (f16*)d_ws;                       // 256 KB
        f16* wlo = (f16*)d_ws + (size_t)HH_ * KK_;   // 256 KB
        w_split<<<128, 256, 0, stream>>>(W, whi, wlo);
        wx_gemm_tile<<<4096, 512, 0, stream>>>(x, whi, wlo, out);
        lif_scan_opt<<<256, 64, 0, stream>>>(out, alpha, u0, s0);
    } else {
        const int M = B * T;
        gemm_naive<<<(M * H + 255) / 256, 256, 0, stream>>>(x, W, out, M, H, I);
        lif_scan_inplace<<<(B * H + 63) / 64, 64, 0, stream>>>(out, alpha, u0, s0, T, H);
    }
}

// Round 12
// 299.462 us; speedup vs baseline: 1.2620x; 1.2620x over previous
//
#include <hip/hip_runtime.h>

#define ALPHA_MIN 0.8187307530779818f  // exp(-1/5)
#define ALPHA_MAX 0.9607894391523232f  // exp(-1/25)

typedef _Float16 f16;
typedef _Float16 f16x4 __attribute__((ext_vector_type(4)));
typedef _Float16 f16x8 __attribute__((ext_vector_type(8)));
typedef float f32x16 __attribute__((ext_vector_type(16)));

// Fixed problem shape
#define BB_ 32
#define TT_ 2048
#define KK_ 256
#define HH_ 512

// ================= kernel 0: W -> fragment-major hi/lo planes ===============
// R12: R11's block latency (~10-20 us for ~3k cyc of work) is a TA request
// storm: per-lane 16 B W-loads at 512 B stride = 64 line-requests/instr,
// 32k requests/block. Fix: pre-arrange W so each wave's fragment loads are
// CONTIGUOUS. Layout WF[hg][ks][lane][8], hg=hh*8+wv (16 groups), ks=0..15,
// lane=0..63: lane's f16x8 = split of W[(hg*32+(lane&31))*256 + ks*16 +
// (lane>>5)*8 .. +8] — bit-identical fragment values to the verified kernel.
__global__ __launch_bounds__(256) void w_frag(
    const float* __restrict__ W, f16* __restrict__ WhiF, f16* __restrict__ WloF)
{
    const int t = blockIdx.x * 256 + threadIdx.x;   // grid 64 -> 0..16383
    const int lane = t & 63;
    const int ks   = (t >> 6) & 15;
    const int hg   = t >> 10;                       // 0..15
    const int fm   = lane & 31;
    const int fq   = lane >> 5;
    const float* src = W + (size_t)(hg * 32 + fm) * KK_ + ks * 16 + fq * 8;
    f16x8 h, l;
#pragma unroll
    for (int j = 0; j < 8; ++j) {
        const float v = src[j];
        const f16 hj = (f16)v;
        h[j] = hj;
        l[j] = (f16)((v - (float)hj) * 2048.0f);
    }
    *(f16x8*)(WhiF + (size_t)t * 8) = h;
    *(f16x8*)(WloF + (size_t)t * 8) = l;
}

// ====================== kernel 1: single-chunk tile GEMM ====================
// Identical to R11's wx_gemm_tile EXCEPT the W-fragment loads: now one
// contiguous 1 KB read per (ks, plane) per wave (16 line-reqs vs 64 scattered)
// -> W request count per block drops ~64x. Block = ONE 32t x 256h tile:
// stage X once (coalesced, hi/lo split, XOR-swizzled LDS), ONE barrier,
// 48 MFMA/wave, retire. 4096 blocks.
// fp16-split: C = Ah*Bh + 2^-11*(Ah*Bl + Al*Bh); bit-identical fragments,
// MFMA order (ks=0..15), and epilogue row mapping vs the verified kernel.
__global__ __launch_bounds__(512, 1) void wx_gemm_tile2(
    const float* __restrict__ X,      // (B,T,K)
    const f16* __restrict__ WhiF,     // fragment-major hi plane
    const f16* __restrict__ WloF,     // fragment-major lo plane
    float* __restrict__ out)          // (B,T,H) <- Wx
{
    __shared__ f16 Ah[32 * 256];      // 16 KB
    __shared__ f16 Al[32 * 256];      // 16 KB

    const int bid = blockIdx.x;
    const int b   = bid & 31;         // XCD = b%8: the 128 chunk-blocks of
    const int ck  = bid >> 5;         // batch b share X[b] in one XCD L2
    const int hh  = ck & 1;           // h-half (0: h<256, 1: h>=256)
    const int tc  = ck >> 1;          // 0..63 t-chunk
    const int t0  = tc * 32;

    const int tid  = threadIdx.x;
    const int wv   = tid >> 6;        // 0..7
    const int lane = tid & 63;
    const int fm   = lane & 31;
    const int fq   = lane >> 5;

    const int hg = hh * 8 + wv;       // fragment group
    const int h0 = hh * 256 + wv * 32;

    // ---- W fragments: contiguous per-wave loads (1 KB/instr) --------------
    f16x8 bh[16], bl[16];
    {
        const f16* wph = WhiF + ((size_t)hg * 1024 + lane) * 8;  // +ks*512
        const f16* wpl = WloF + ((size_t)hg * 1024 + lane) * 8;
#pragma unroll
        for (int ks = 0; ks < 16; ++ks) {
            bh[ks] = *(const f16x8*)(wph + ks * 512);
            bl[ks] = *(const f16x8*)(wpl + ks * 512);
        }
    }

    // ---- stage X chunk: 2048 slots of 4 floats, fully coalesced -----------
    {
        const float* xb = X + ((size_t)b * TT_ + t0) * KK_;
        float4 v[4];
#pragma unroll
        for (int i = 0; i < 4; ++i)
            v[i] = *(const float4*)(xb + (size_t)(tid + i * 512) * 4);
#pragma unroll
        for (int i = 0; i < 4; ++i) {
            const int s  = tid + i * 512;          // slot 0..2047
            const int r  = s >> 6;                 // t-row 0..31
            const int k0 = (s & 63) * 4;           // f16-unit col
            const int kk = k0 ^ ((r & 7) << 3);    // XOR swizzle (bank spread)
            const float vv[4] = {v[i].x, v[i].y, v[i].z, v[i].w};
            f16x4 h, l;
#pragma unroll
            for (int e = 0; e < 4; ++e) {
                const f16 he = (f16)vv[e];
                h[e] = he;
                l[e] = (f16)((vv[e] - (float)he) * 2048.0f);
            }
            *(f16x4*)&Ah[r * 256 + kk] = h;
            *(f16x4*)&Al[r * 256 + kk] = l;
        }
    }
    __syncthreads();                  // the block's ONE barrier

    // ---- 48 MFMA: 16 k-steps x 3 accumulators -----------------------------
    f32x16 accH, accLa, accLb;
#pragma unroll
    for (int e = 0; e < 16; ++e) { accH[e] = 0.0f; accLa[e] = 0.0f; accLb[e] = 0.0f; }

    const int rsw = (fm & 7) << 3;
#pragma unroll
    for (int ks = 0; ks < 16; ++ks) {
        const int kk = (ks * 16 + fq * 8) ^ rsw;
        const f16x8 ah = *(const f16x8*)&Ah[fm * 256 + kk];
        const f16x8 al = *(const f16x8*)&Al[fm * 256 + kk];
        accH  = __builtin_amdgcn_mfma_f32_32x32x16_f16(ah, bh[ks], accH,  0, 0, 0);
        accLa = __builtin_amdgcn_mfma_f32_32x32x16_f16(ah, bl[ks], accLa, 0, 0, 0);
        accLb = __builtin_amdgcn_mfma_f32_32x32x16_f16(al, bh[ks], accLb, 0, 0, 0);
    }

    // ---- epilogue: proven row mapping, direct global stores ---------------
    float* op = out + ((size_t)b * TT_ + t0) * HH_ + h0 + fm;
#pragma unroll
    for (int r = 0; r < 16; ++r) {
        const int roww = (r & 3) + 8 * (r >> 2) + 4 * fq;
        op[(size_t)roww * HH_] = accH[r] + (accLa[r] + accLb[r]) * (1.0f / 2048.0f);
    }
}

// ============================ kernel 2: scan ================================
// R4's proven scan (~55 us, ~4.9 TB/s effective): 256 blocks x 64 threads,
// in-place on out, depth-32 A/B register prefetch. Unchanged.
__global__ __launch_bounds__(64) void lif_scan_opt(
    float* __restrict__ buf,          // (B,T,H): in Wx, out spikes
    const float* __restrict__ alpha,
    const float* __restrict__ u0,
    const float* __restrict__ s0)
{
    const int chain = blockIdx.x * 64 + threadIdx.x;   // 0..16383
    const int h = chain & (HH_ - 1);
    const int b = chain >> 9;
    float a = alpha[h];
    a = fminf(fmaxf(a, ALPHA_MIN), ALPHA_MAX);
    const float bbv = 1.0f - a;
    float u = u0[chain];
    float s = s0[chain];
    float* base = buf + (size_t)b * TT_ * HH_ + h;

    float wA[32], wB[32];
    auto loadA = [&](int t0) {
#pragma unroll
        for (int i = 0; i < 32; ++i) wA[i] = base[(size_t)(t0 + i) * HH_];
    };
    auto loadB = [&](int t0) {
#pragma unroll
        for (int i = 0; i < 32; ++i) wB[i] = base[(size_t)(t0 + i) * HH_];
    };
    auto stepA = [&](int t0) {
#pragma unroll
        for (int i = 0; i < 32; ++i) {
            u = fmaf(a, u - s, bbv * wA[i]);
            s = (u > 1.0f) ? 1.0f : 0.0f;
            base[(size_t)(t0 + i) * HH_] = s;
        }
    };
    auto stepB = [&](int t0) {
#pragma unroll
        for (int i = 0; i < 32; ++i) {
            u = fmaf(a, u - s, bbv * wB[i]);
            s = (u > 1.0f) ? 1.0f : 0.0f;
            base[(size_t)(t0 + i) * HH_] = s;
        }
    };

    loadA(0);
    for (int t0 = 0; t0 < TT_; t0 += 64) {
        loadB(t0 + 32);
        stepA(t0);
        if (t0 + 64 < TT_) loadA(t0 + 64);
        stepB(t0 + 32);
    }
}

// =================== generic fallback (non-reference shapes) ================
__global__ void gemm_naive(const float* __restrict__ X, const float* __restrict__ W,
                           float* __restrict__ C, int M, int N, int K)
{
    const int idx = blockIdx.x * 256 + threadIdx.x;
    if (idx >= M * N) return;
    const int m = idx / N, n = idx % N;
    float acc = 0.0f;
    for (int k = 0; k < K; ++k) acc = fmaf(X[(size_t)m * K + k], W[(size_t)n * K + k], acc);
    C[idx] = acc;
}

__global__ __launch_bounds__(64) void lif_scan_inplace(
    float* __restrict__ buf, const float* __restrict__ alpha,
    const float* __restrict__ u0, const float* __restrict__ s0, int T, int H)
{
    const int chain = blockIdx.x * 64 + threadIdx.x;
    const int h = chain % H;
    const int b = chain / H;
    float a = alpha[h];
    a = fminf(fmaxf(a, ALPHA_MIN), ALPHA_MAX);
    const float bb = 1.0f - a;
    float u = u0[chain], s = s0[chain];
    float* base = buf + (size_t)b * T * H + h;
    for (int t = 0; t < T; ++t) {
        u = fmaf(a, u - s, bb * base[(size_t)t * H]);
        s = (u > 1.0f) ? 1.0f : 0.0f;
        base[(size_t)t * H] = s;
    }
}

// ---------------- launch ----------------------------------------------------
extern "C" void kernel_launch(void* const* d_in, const int* in_sizes, int n_in,
                              void* d_out, int out_size, void* d_ws, size_t ws_size,
                              hipStream_t stream) {
    const float* x     = (const float*)d_in[0];
    const float* W     = (const float*)d_in[1];
    const float* alpha = (const float*)d_in[2];
    const float* u0    = (const float*)d_in[3];
    const float* s0    = (const float*)d_in[4];
    float* out = (float*)d_out;

    const int H = in_sizes[2];
    const int I = in_sizes[1] / H;
    const int B = in_sizes[3] / H;
    const int T = in_sizes[0] / (B * I);

    if (B == BB_ && T == TT_ && I == KK_ && H == HH_ && ws_size >= (1u << 20)) {
        f16* whiF = (f16*)d_ws;                       // 256 KB
        f16* wloF = (f16*)d_ws + (size_t)HH_ * KK_;   // 256 KB
        w_frag<<<64, 256, 0, stream>>>(W, whiF, wloF);
        wx_gemm_tile2<<<4096, 512, 0, stream>>>(x, whiF, wloF, out);
        lif_scan_opt<<<256, 64, 0, stream>>>(out, alpha, u0, s0);
    } else {
        const int M = B * T;
        gemm_naive<<<(M * H + 255) / 256, 256, 0, stream>>>(x, W, out, M, H, I);
        lif_scan_inplace<<<(B * H + 63) / 64, 64, 0, stream>>>(out, alpha, u0, s0, T, H);
    }
}